// Round 1
// 96.870 us; speedup vs baseline: 1.0180x; 1.0180x over previous
//
#include <hip/hip_runtime.h>

// Round 14: occupancy attack. r13 was latency-bound at 8 waves/CU (LDS-limited:
// 72.8 KB per 4-wave block -> 2 blocks/CU, no pipe >50%). Now: 1-wave blocks
// (grid 2048), LDS cut 18.2 KB/wave -> 14.08 KB/wave => 11 waves/CU (+38%):
//  - Smh 48x72 -> 40x40 shorts (stride 40 = 20-bank rotate, ~2-way reads);
//    the K/M zero-padding rows/cols now come from predicated zero registers.
//  - pair table -> per-lane register arithmetic (no LDS table, no byte-loads
//    at tile-chain head, NO barrier at all: kernel is wave-synchronous).
//  - __launch_bounds__(64,3) caps VGPR ~168 so regfile sustains 3 waves/SIMD.
// Free riders: bias/zero folded into first MFMA C-operand (-32 v_mov/tile);
// epilogue proj dot split into 4 partial FMA chains (serial latency /4).

#define NF 40
#define ED 64
#define AS 32
#define XS_STRIDE 68   // floats; 272 B rows, 16B-aligned, 4-bank rotate/row
#define SM_STRIDE 40   // shorts; 80 B rows, 16B-aligned, 20-bank rotate/row

typedef __attribute__((ext_vector_type(4))) float f32x4;
typedef __attribute__((ext_vector_type(16))) float f32x16;
typedef __attribute__((ext_vector_type(8))) short bf16x8;

union ABFrag { bf16x8 v; unsigned int u[4]; uint4 q; };

// bf16 round-half-up: bits(f)+0x8000 >> 16. == RNE except on exact ties.
__device__ __forceinline__ unsigned short bfbits_rn(float f) {
  return (unsigned short)((__float_as_uint(f) + 0x8000u) >> 16);
}
// pack2: (bf16(a)) | (bf16(b) << 16) in 3 VALU (2 adds + v_perm byte-pack).
__device__ __forceinline__ unsigned int pack2(float a, float b) {
  unsigned int ua = __float_as_uint(a) + 0x8000u;
  unsigned int ub = __float_as_uint(b) + 0x8000u;
  return __builtin_amdgcn_perm(ub, ua, 0x07060302u);
}
// split: hi = pack2(a,b); lo = pack2 of the exact residuals.
__device__ __forceinline__ void split_pack(float a, float b,
                                           unsigned int& hi, unsigned int& lo) {
  hi = pack2(a, b);
  float ra = a - __uint_as_float(hi << 16);
  float rb = b - __uint_as_float(hi & 0xffff0000u);
  lo = pack2(ra, rb);
}

__global__ __launch_bounds__(64, 3) void afm_kernel(
    const float* __restrict__ x, const float* __restrict__ attn_w,
    const float* __restrict__ attn_b, const float* __restrict__ proj_w,
    const float* __restrict__ proj_b, const float* __restrict__ fc_w,
    const float* __restrict__ fc_b, float* __restrict__ out) {
  __shared__ __align__(16) float xs[NF * XS_STRIDE];            // 10880 B
  __shared__ __align__(16) unsigned short Smh[NF * SM_STRIDE];  // 3200 B

  const int lane = threadIdx.x;      // one wave per block
  const int quad = lane >> 4;
  const int col = lane & 15;
  const int half = lane >> 5;        // 32x32 MFMA k-half
  const int m32 = lane & 31;         // 32x32 MFMA row/col index
  const int i_off = m32 >> 3;        // rect-tile row-within-tile
  const int jr_off = m32 & 7;        // rect-tile col-within-tile
  const int row = blockIdx.x;
  const float* xg = x + row * (NF * ED);

  // ---- P1: stage x row (10 float4/lane), zero Smh.
#pragma unroll
  for (int v = 0; v < 10; ++v) {
    int e4 = v * 64 + lane;           // 640 float4 per row
    int f = e4 >> 4, c4 = e4 & 15;
    *(float4*)(xs + f * XS_STRIDE + c4 * 4) = *(const float4*)(xg + e4 * 4);
  }
#pragma unroll
  for (int v = 0; v < 13; ++v) {      // 800 u32
    int e = v * 64 + lane;
    if (e < (NF * SM_STRIDE) / 2) ((unsigned int*)Smh)[e] = 0u;
  }

  // ---- per-lane constants.
  // A-frag (32x32x16): A[mrow=m32][k=half*8+e]; A = W^T -> w[d][a=m32].
  ABFrag fwh[4], fwl[4];
#pragma unroll
  for (int s4 = 0; s4 < 4; ++s4)
#pragma unroll
    for (int p = 0; p < 4; ++p) {
      int d = s4 * 16 + half * 8 + 2 * p;
      split_pack(attn_w[d * AS + m32], attn_w[(d + 1) * AS + m32],
                 fwh[s4].u[p], fwl[s4].u[p]);
    }
  // Epilogue constants: C/D row(reg) = (reg&3) + 8*(reg>>2) + 4*half.
  // ABV/Z16 are persistent vectors fed to the first MFMA C-operand of each
  // accumulator chain (kills the 32 per-tile acc-init movs).
  f32x16 ABV, Z16;
  float pwv[16];
#pragma unroll
  for (int r = 0; r < 16; ++r) {
    int arow = (r & 3) + 8 * (r >> 2) + 4 * half;
    ABV[r] = attn_b[arow];
    pwv[r] = proj_w[arow];
    Z16[r] = 0.f;
  }
  const float fcb = fc_b[0];

  // ---- diagonal-tile decode (once per lane): triu-of-8, 28 pairs + 4 pads.
  int dmm = (m32 < 28) ? m32 : 0;
  int da = 0;
  while (dmm >= 7 - da) { dmm -= 7 - da; ++da; }
  const int a_off = da;
  const int j_off = da + 1 + dmm;
  const bool dpad = (m32 >= 28);

  // ---- P2 tile body: 32x32x16 MFMA (pairs on N), K=64 over 4 sub-chunks,
  // hi/lo W split on two accumulator chains; fused relu+proj dot -> logit.
  auto tile_lg = [&](int fi, int fj) -> float {
    const float* xi = xs + fi * XS_STRIDE + half * 8;
    const float* xj = xs + fj * XS_STRIDE + half * 8;
    f32x16 acc0, acc1;
#pragma unroll
    for (int s4 = 0; s4 < 4; ++s4) {
      float4 i0 = *(const float4*)(xi + s4 * 16);
      float4 i1 = *(const float4*)(xi + s4 * 16 + 4);
      float4 j0 = *(const float4*)(xj + s4 * 16);
      float4 j1 = *(const float4*)(xj + s4 * 16 + 4);
      ABFrag ip;  // B-frag: B[k=half*8+e][n=m32] = ip[pair][d]
      ip.u[0] = pack2(i0.x * j0.x, i0.y * j0.y);
      ip.u[1] = pack2(i0.z * j0.z, i0.w * j0.w);
      ip.u[2] = pack2(i1.x * j1.x, i1.y * j1.y);
      ip.u[3] = pack2(i1.z * j1.z, i1.w * j1.w);
      if (s4 == 0) {
        acc0 = __builtin_amdgcn_mfma_f32_32x32x16_bf16(fwh[0].v, ip.v, ABV, 0, 0, 0);
        acc0 = __builtin_amdgcn_mfma_f32_32x32x16_bf16(fwl[0].v, ip.v, acc0, 0, 0, 0);
      } else if (s4 == 1) {
        acc1 = __builtin_amdgcn_mfma_f32_32x32x16_bf16(fwh[1].v, ip.v, Z16, 0, 0, 0);
        acc1 = __builtin_amdgcn_mfma_f32_32x32x16_bf16(fwl[1].v, ip.v, acc1, 0, 0, 0);
      } else if (s4 & 1) {
        acc1 = __builtin_amdgcn_mfma_f32_32x32x16_bf16(fwh[s4].v, ip.v, acc1, 0, 0, 0);
        acc1 = __builtin_amdgcn_mfma_f32_32x32x16_bf16(fwl[s4].v, ip.v, acc1, 0, 0, 0);
      } else {
        acc0 = __builtin_amdgcn_mfma_f32_32x32x16_bf16(fwh[s4].v, ip.v, acc0, 0, 0, 0);
        acc0 = __builtin_amdgcn_mfma_f32_32x32x16_bf16(fwl[s4].v, ip.v, acc0, 0, 0, 0);
      }
    }
    float lg0 = 0.f, lg1 = 0.f, lg2 = 0.f, lg3 = 0.f;  // 4 partial chains
#pragma unroll
    for (int r = 0; r < 4; ++r) {
      lg0 = fmaf(fmaxf(acc0[r] + acc1[r], 0.f), pwv[r], lg0);
      lg1 = fmaf(fmaxf(acc0[r + 4] + acc1[r + 4], 0.f), pwv[r + 4], lg1);
      lg2 = fmaf(fmaxf(acc0[r + 8] + acc1[r + 8], 0.f), pwv[r + 8], lg2);
      lg3 = fmaf(fmaxf(acc0[r + 12] + acc1[r + 12], 0.f), pwv[r + 12], lg3);
    }
    float lg = (lg0 + lg1) + (lg2 + lg3);
    lg += __shfl_xor(lg, 32);  // combine the two k-halves
    return lg;
  };

  // ---- P2: 20 rect tiles (4i x 8j, no pads) + 5 diagonal tiles.
  // No max-subtract (|logit| << 88). Smh stores raw exp in bf16.
  float lsum = 0.f;
  for (int t = 0; t < 20; ++t) {
    const int j0 = 1 + (t >= 2) + (t >= 6) + (t >= 12);           // uniform
    const int tb = (t >= 12) ? 12 : (t >= 6) ? 6 : (t >= 2) ? 2 : 0;
    const int fi = (t - tb) * 4 + i_off;
    const int fj = j0 * 8 + jr_off;
    float lg = tile_lg(fi, fj);
    if (lane < 32) {
      float e = __expf(lg);
      Smh[fi * SM_STRIDE + fj] = bfbits_rn(e);
      lsum += e;
    }
  }
  for (int k = 0; k < 5; ++k) {
    const int fi = 8 * k + a_off;
    const int fj = 8 * k + j_off;
    float lg = tile_lg(fi, fj);
    if ((lane < 32) & !dpad) {
      float e = __expf(lg);
      Smh[fi * SM_STRIDE + fj] = bfbits_rn(e);
      lsum += e;
    }
  }
#pragma unroll
  for (int off = 1; off <= 32; off <<= 1) lsum += __shfl_xor(lsum, off);
  const float total = lsum;  // this row's softmax denominator (all lanes)

  // ---- P4: M = S_up @ X via 16x16x32 MFMA; attn[d] = sum_i x_i[d]*M[i][d].
  // S rows >=40 and cols >=40 are zero: supplied from registers (not LDS).
  ABFrag fsh[3][2];
  const uint4 z4 = make_uint4(0u, 0u, 0u, 0u);
#pragma unroll
  for (int it = 0; it < 3; ++it) {
    const bool vr = (it < 2) | (col < 8);  // S row it*16+col < 40
    const unsigned short* srow = Smh + (it * 16 + col) * SM_STRIDE;
    fsh[it][0].q = vr ? *(const uint4*)(srow + quad * 8) : z4;          // k 0..31
    fsh[it][1].q = (vr & (quad == 0)) ? *(const uint4*)(srow + 32) : z4; // k 32..39
  }
  float ypart = 0.f;
#pragma unroll
  for (int nt = 0; nt < 4; ++nt) {
    const int dcol = nt * 16 + col;
    ABFrag fxh[2], fxl[2];
#pragma unroll
    for (int kt = 0; kt < 2; ++kt) {
      const int kbase = kt * 32 + quad * 8;
      if ((kt == 0) | (quad == 0)) {  // k < 40
#pragma unroll
        for (int p = 0; p < 4; ++p) {
          float v0 = xs[(kbase + 2 * p) * XS_STRIDE + dcol];
          float v1 = xs[(kbase + 2 * p + 1) * XS_STRIDE + dcol];
          split_pack(v0, v1, fxh[kt].u[p], fxl[kt].u[p]);
        }
      } else {
        fxh[kt].q = z4;
        fxl[kt].q = z4;
      }
    }
    f32x4 mac[3];
#pragma unroll
    for (int it = 0; it < 3; ++it) {
      f32x4 z = {0.f, 0.f, 0.f, 0.f};
      z = __builtin_amdgcn_mfma_f32_16x16x32_bf16(fsh[it][0].v, fxh[0].v, z, 0, 0, 0);
      z = __builtin_amdgcn_mfma_f32_16x16x32_bf16(fsh[it][1].v, fxh[1].v, z, 0, 0, 0);
      z = __builtin_amdgcn_mfma_f32_16x16x32_bf16(fsh[it][0].v, fxl[0].v, z, 0, 0, 0);
      z = __builtin_amdgcn_mfma_f32_16x16x32_bf16(fsh[it][1].v, fxl[1].v, z, 0, 0, 0);
      mac[it] = z;
    }
    float part = 0.f;
#pragma unroll
    for (int r = 0; r < 4; ++r)
      part = fmaf(mac[0][r], xs[(quad * 4 + r) * XS_STRIDE + dcol], part);
#pragma unroll
    for (int r = 0; r < 4; ++r)
      part = fmaf(mac[1][r], xs[(16 + quad * 4 + r) * XS_STRIDE + dcol], part);
    if (quad < 2) {
#pragma unroll
      for (int r = 0; r < 4; ++r)
        part = fmaf(mac[2][r], xs[(32 + quad * 4 + r) * XS_STRIDE + dcol], part);
    }
    part += __shfl_xor(part, 16);  // reduce over quads (i groups)
    part += __shfl_xor(part, 32);
    ypart = fmaf(part, fc_w[dcol], ypart);
  }
#pragma unroll
  for (int off = 1; off <= 8; off <<= 1) ypart += __shfl_xor(ypart, off);
  if (lane == 0) out[row] = ypart / total + fcb;
  (void)proj_b;  // cancels in softmax
}

extern "C" void kernel_launch(void* const* d_in, const int* in_sizes, int n_in,
                              void* d_out, int out_size, void* d_ws, size_t ws_size,
                              hipStream_t stream) {
  (void)in_sizes; (void)n_in; (void)out_size; (void)d_ws; (void)ws_size;
  afm_kernel<<<2048, 64, 0, stream>>>(
      (const float*)d_in[0], (const float*)d_in[1], (const float*)d_in[2],
      (const float*)d_in[3], (const float*)d_in[4], (const float*)d_in[5],
      (const float*)d_in[6], (float*)d_out);
}